// Round 1
// baseline (570.975 us; speedup 1.0000x reference)
//
#include <hip/hip_runtime.h>
#include <stdint.h>

#define NTHREADS 512   // 8 waves
#define TILE_N   256   // cols per block (4 per lane, 64 lanes)
#define TILE_M   16    // rows per block (2 per wave, 8 waves)
#define CPL      4     // cols per lane
#define RPW      2     // rows per wave
#define KCHUNK   16

__device__ __forceinline__ uint32_t pack4f(float4 f) {
  int x = (int)f.x, y = (int)f.y, z = (int)f.z, w = (int)f.w;
  x = min(max(x, 0), 255); y = min(max(y, 0), 255);
  z = min(max(z, 0), 255); w = min(max(w, 0), 255);
  return (uint32_t)x | ((uint32_t)y << 8) | ((uint32_t)z << 16) | ((uint32_t)w << 24);
}

__device__ __forceinline__ uint32_t bsel(const uint4& v, int kk) {
  uint32_t word = (kk < 4) ? v.x : (kk < 8) ? v.y : (kk < 12) ? v.z : v.w;
  return (word >> ((kk & 3) * 8)) & 255u;
}

// 256x256 int32 LUT -> u8
__global__ __launch_bounds__(256) void pack_lut_k(const int* __restrict__ lut,
                                                  uint8_t* __restrict__ out, int n16) {
  int t = blockIdx.x * 256 + threadIdx.x;
  if (t >= n16) return;
  const int4* s = (const int4*)lut;
  uint32_t w[4];
#pragma unroll
  for (int q = 0; q < 4; q++) {
    int4 v = s[t * 4 + q];
    w[q] = (uint32_t)(v.x & 255) | ((uint32_t)(v.y & 255) << 8) |
           ((uint32_t)(v.z & 255) << 16) | ((uint32_t)(v.w & 255) << 24);
  }
  ((uint4*)out)[t] = make_uint4(w[0], w[1], w[2], w[3]);
}

// input [M][K] f32 codes -> u8 codes (same layout)
__global__ __launch_bounds__(256) void pack_a_k(const float* __restrict__ a,
                                                 uint8_t* __restrict__ out, int n16) {
  int t = blockIdx.x * 256 + threadIdx.x;
  if (t >= n16) return;
  const float4* s = (const float4*)a;
  uint32_t w[4];
#pragma unroll
  for (int q = 0; q < 4; q++) w[q] = pack4f(s[t * 4 + q]);
  ((uint4*)out)[t] = make_uint4(w[0], w[1], w[2], w[3]);
}

// weight [N][K] f32 -> Wt chunk-transposed [K/16][N][16] u8 (coalesced main-loop reads)
__global__ __launch_bounds__(256) void pack_w_k(const float* __restrict__ w,
                                                 uint8_t* __restrict__ out, int N, int K) {
  int t = blockIdx.x * 256 + threadIdx.x;
  int cpk = K >> 4;
  if (t >= N * cpk) return;
  int n = t / cpk, c = t - n * cpk;
  const float4* s = (const float4*)(w + (size_t)n * K + (size_t)c * 16);
  uint32_t x0 = pack4f(s[0]), x1 = pack4f(s[1]), x2 = pack4f(s[2]), x3 = pack4f(s[3]);
  *(uint4*)(out + ((size_t)c * N + n) * 16) = make_uint4(x0, x1, x2, x3);
}

// Main: LUT staged as u8 in LDS. Each gather instruction has wave-uniform `a`
// (LUT row) -> bank = w[6:2], <=2 distinct words per bank -> conflict-free.
__global__ __launch_bounds__(NTHREADS, 4) void lutmm_packed(
    const uint8_t* __restrict__ A,   // [M][K] u8
    const uint8_t* __restrict__ Wt,  // [K/16][N][16] u8
    const uint8_t* __restrict__ LUT, // [256][256] u8
    const float* __restrict__ bias,
    float* __restrict__ out, int M, int N, int K) {
  __shared__ uint8_t lut[65536];
  {
    const uint4* s = (const uint4*)LUT;
    uint4* d = (uint4*)lut;
#pragma unroll
    for (int i = 0; i < 8; i++) d[threadIdx.x + i * NTHREADS] = s[threadIdx.x + i * NTHREADS];
  }
  __syncthreads();

  const int tid = threadIdx.x;
  const int lane = tid & 63;
  const int wid = tid >> 6;
  const int r0 = blockIdx.y * TILE_M + wid * RPW;
  const int cbase = blockIdx.x * TILE_N + lane;
  uint32_t acc[RPW][CPL] = {};
  const size_t chunk_stride = (size_t)N * 16;

  for (int kb = 0; kb < K; kb += KCHUNK) {
    uint4 ap[RPW], wp[CPL];
#pragma unroll
    for (int i = 0; i < RPW; i++)
      ap[i] = *(const uint4*)(A + (size_t)(r0 + i) * K + kb);
    const uint8_t* wtb = Wt + (size_t)(kb >> 4) * chunk_stride;
#pragma unroll
    for (int j = 0; j < CPL; j++)
      wp[j] = *(const uint4*)(wtb + (size_t)(cbase + j * 64) * 16);
#pragma unroll
    for (int kk = 0; kk < KCHUNK; kk++) {
      uint32_t as[RPW], ws[CPL];
#pragma unroll
      for (int i = 0; i < RPW; i++) as[i] = bsel(ap[i], kk) << 8;
#pragma unroll
      for (int j = 0; j < CPL; j++) ws[j] = bsel(wp[j], kk);
#pragma unroll
      for (int i = 0; i < RPW; i++)
#pragma unroll
        for (int j = 0; j < CPL; j++)
          acc[i][j] += lut[as[i] + ws[j]];
    }
  }

#pragma unroll
  for (int i = 0; i < RPW; i++) {
    int r = r0 + i;
#pragma unroll
    for (int j = 0; j < CPL; j++) {
      int c = cbase + j * 64;
      out[(size_t)r * N + c] = (float)acc[i][j] + bias[c];
    }
  }
}

// Fallback if ws too small: read f32 codes directly (same structure, inline convert).
__global__ __launch_bounds__(NTHREADS, 4) void lutmm_f32(
    const float* __restrict__ A, const float* __restrict__ W,
    const int* __restrict__ LUT32, const float* __restrict__ bias,
    float* __restrict__ out, int M, int N, int K) {
  __shared__ uint8_t lut[65536];
  for (int i = threadIdx.x; i < 16384; i += NTHREADS) {
    int4 v = ((const int4*)LUT32)[i];
    ((uint32_t*)lut)[i] = (uint32_t)(v.x & 255) | ((uint32_t)(v.y & 255) << 8) |
                          ((uint32_t)(v.z & 255) << 16) | ((uint32_t)(v.w & 255) << 24);
  }
  __syncthreads();

  const int tid = threadIdx.x;
  const int lane = tid & 63;
  const int wid = tid >> 6;
  const int r0 = blockIdx.y * TILE_M + wid * RPW;
  const int cbase = blockIdx.x * TILE_N + lane;
  uint32_t acc[RPW][CPL] = {};

  for (int kb = 0; kb < K; kb += KCHUNK) {
    uint4 ap[RPW], wp[CPL];
#pragma unroll
    for (int i = 0; i < RPW; i++) {
      const float4* s = (const float4*)(A + (size_t)(r0 + i) * K + kb);
      ap[i] = make_uint4(pack4f(s[0]), pack4f(s[1]), pack4f(s[2]), pack4f(s[3]));
    }
#pragma unroll
    for (int j = 0; j < CPL; j++) {
      const float4* s = (const float4*)(W + (size_t)(cbase + j * 64) * K + kb);
      wp[j] = make_uint4(pack4f(s[0]), pack4f(s[1]), pack4f(s[2]), pack4f(s[3]));
    }
#pragma unroll
    for (int kk = 0; kk < KCHUNK; kk++) {
      uint32_t as[RPW], ws[CPL];
#pragma unroll
      for (int i = 0; i < RPW; i++) as[i] = bsel(ap[i], kk) << 8;
#pragma unroll
      for (int j = 0; j < CPL; j++) ws[j] = bsel(wp[j], kk);
#pragma unroll
      for (int i = 0; i < RPW; i++)
#pragma unroll
        for (int j = 0; j < CPL; j++)
          acc[i][j] += lut[as[i] + ws[j]];
    }
  }

#pragma unroll
  for (int i = 0; i < RPW; i++) {
    int r = r0 + i;
#pragma unroll
    for (int j = 0; j < CPL; j++) {
      int c = cbase + j * 64;
      out[(size_t)r * N + c] = (float)acc[i][j] + bias[c];
    }
  }
}

extern "C" void kernel_launch(void* const* d_in, const int* in_sizes, int n_in,
                              void* d_out, int out_size, void* d_ws, size_t ws_size,
                              hipStream_t stream) {
  const float* inp  = (const float*)d_in[0];  // [M][K]
  const float* wgt  = (const float*)d_in[1];  // [N][K]
  const float* bias = (const float*)d_in[2];  // [N]
  const int*   lut  = (const int*)d_in[3];    // [256][256]

  const int N = in_sizes[2];
  const int K = in_sizes[1] / N;
  const int M = in_sizes[0] / K;
  float* out = (float*)d_out;

  dim3 grid(N / TILE_N, M / TILE_M);
  size_t need = 65536 + (size_t)M * K + (size_t)N * K;

  if (ws_size >= need) {
    uint8_t* lut8 = (uint8_t*)d_ws;
    uint8_t* a8   = lut8 + 65536;
    uint8_t* wt8  = a8 + (size_t)M * K;
    pack_lut_k<<<16, 256, 0, stream>>>(lut, lut8, 65536 / 16);
    int an16 = (M * K) / 16;
    pack_a_k<<<(an16 + 255) / 256, 256, 0, stream>>>(inp, a8, an16);
    int wn16 = (N * K) / 16;
    pack_w_k<<<(wn16 + 255) / 256, 256, 0, stream>>>(wgt, wt8, N, K);
    lutmm_packed<<<grid, NTHREADS, 0, stream>>>(a8, wt8, lut8, bias, out, M, N, K);
  } else {
    lutmm_f32<<<grid, NTHREADS, 0, stream>>>(inp, wgt, lut, bias, out, M, N, K);
  }
}

// Round 4
// 558.790 us; speedup vs baseline: 1.0218x; 1.0218x over previous
//
#include <hip/hip_runtime.h>
#include <stdint.h>

#define NTHREADS 1024  // 16 waves
#define TILE_N   256   // cols per block (4 per lane, 64 lanes)
#define TILE_M   16    // rows per block (1 per wave, 16 waves)
#define CPL      4     // cols per lane
#define KCHUNK   16

__device__ __forceinline__ uint32_t pack4f(float4 f) {
  int x = (int)f.x, y = (int)f.y, z = (int)f.z, w = (int)f.w;
  x = min(max(x, 0), 255); y = min(max(y, 0), 255);
  z = min(max(z, 0), 255); w = min(max(w, 0), 255);
  return (uint32_t)x | ((uint32_t)y << 8) | ((uint32_t)z << 16) | ((uint32_t)w << 24);
}

__device__ __forceinline__ uint32_t bsel(const uint4& v, int kk) {
  uint32_t word = (kk < 4) ? v.x : (kk < 8) ? v.y : (kk < 12) ? v.z : v.w;
  return (word >> ((kk & 3) * 8)) & 255u;
}

// 256x256 int32 LUT -> u8
__global__ __launch_bounds__(256) void pack_lut_k(const int* __restrict__ lut,
                                                  uint8_t* __restrict__ out, int n16) {
  int t = blockIdx.x * 256 + threadIdx.x;
  if (t >= n16) return;
  const int4* s = (const int4*)lut;
  uint32_t w[4];
#pragma unroll
  for (int q = 0; q < 4; q++) {
    int4 v = s[t * 4 + q];
    w[q] = (uint32_t)(v.x & 255) | ((uint32_t)(v.y & 255) << 8) |
           ((uint32_t)(v.z & 255) << 16) | ((uint32_t)(v.w & 255) << 24);
  }
  ((uint4*)out)[t] = make_uint4(w[0], w[1], w[2], w[3]);
}

// input [M][K] f32 codes -> u8 codes (same layout)
__global__ __launch_bounds__(256) void pack_a_k(const float* __restrict__ a,
                                                 uint8_t* __restrict__ out, int n16) {
  int t = blockIdx.x * 256 + threadIdx.x;
  if (t >= n16) return;
  const float4* s = (const float4*)a;
  uint32_t w[4];
#pragma unroll
  for (int q = 0; q < 4; q++) w[q] = pack4f(s[t * 4 + q]);
  ((uint4*)out)[t] = make_uint4(w[0], w[1], w[2], w[3]);
}

// weight [N][K] f32 -> Wt chunk-transposed [K/16][N][16] u8 (coalesced main-loop reads)
__global__ __launch_bounds__(256) void pack_w_k(const float* __restrict__ w,
                                                 uint8_t* __restrict__ out, int N, int K) {
  int t = blockIdx.x * 256 + threadIdx.x;
  int cpk = K >> 4;
  if (t >= N * cpk) return;
  int n = t / cpk, c = t - n * cpk;
  const float4* s = (const float4*)(w + (size_t)n * K + (size_t)c * 16);
  uint32_t x0 = pack4f(s[0]), x1 = pack4f(s[1]), x2 = pack4f(s[2]), x3 = pack4f(s[3]);
  *(uint4*)(out + ((size_t)c * N + n) * 16) = make_uint4(x0, x1, x2, x3);
}

// Main: 16-wave blocks, 64KB u8 LUT in LDS, 2 blocks/CU -> 32 waves/CU.
// Each wave owns 1 output row (A-codes wave-uniform); each lane owns 4 cols.
__global__ __launch_bounds__(NTHREADS, 8) void lutmm_packed(
    const uint8_t* __restrict__ A,   // [M][K] u8
    const uint8_t* __restrict__ Wt,  // [K/16][N][16] u8
    const uint8_t* __restrict__ LUT, // [256][256] u8
    const float* __restrict__ bias,
    float* __restrict__ out, int M, int N, int K) {
  __shared__ uint8_t lut[65536];
  {
    const uint4* s = (const uint4*)LUT;
    uint4* d = (uint4*)lut;
#pragma unroll
    for (int i = 0; i < 4; i++) d[threadIdx.x + i * NTHREADS] = s[threadIdx.x + i * NTHREADS];
  }
  __syncthreads();

  const int tid = threadIdx.x;
  const int lane = tid & 63;
  const int wid = tid >> 6;
  const int r0 = blockIdx.y * TILE_M + wid;      // 1 row per wave
  const int cbase = blockIdx.x * TILE_N + lane;
  uint32_t acc[CPL] = {};
  const size_t chunk_stride = (size_t)N * 16;

  for (int kb = 0; kb < K; kb += KCHUNK) {
    uint4 ap = *(const uint4*)(A + (size_t)r0 * K + kb);  // wave-uniform (broadcast)
    const uint8_t* wtb = Wt + (size_t)(kb >> 4) * chunk_stride;
    uint4 wp[CPL];
#pragma unroll
    for (int j = 0; j < CPL; j++)
      wp[j] = *(const uint4*)(wtb + (size_t)(cbase + j * 64) * 16);
#pragma unroll
    for (int kk = 0; kk < KCHUNK; kk++) {
      uint32_t as = bsel(ap, kk) << 8;   // wave-uniform LUT row base
      uint32_t ws[CPL];
#pragma unroll
      for (int j = 0; j < CPL; j++) ws[j] = bsel(wp[j], kk);
#pragma unroll
      for (int j = 0; j < CPL; j++)
        acc[j] += lut[as | ws[j]];
    }
  }

#pragma unroll
  for (int j = 0; j < CPL; j++) {
    int c = cbase + j * 64;
    out[(size_t)r0 * N + c] = (float)acc[j] + bias[c];
  }
}

// Fallback if ws too small: read f32 codes directly (same structure, inline convert).
__global__ __launch_bounds__(NTHREADS, 8) void lutmm_f32(
    const float* __restrict__ A, const float* __restrict__ W,
    const int* __restrict__ LUT32, const float* __restrict__ bias,
    float* __restrict__ out, int M, int N, int K) {
  __shared__ uint8_t lut[65536];
  for (int i = threadIdx.x; i < 16384; i += NTHREADS) {
    int4 v = ((const int4*)LUT32)[i];
    ((uint32_t*)lut)[i] = (uint32_t)(v.x & 255) | ((uint32_t)(v.y & 255) << 8) |
                          ((uint32_t)(v.z & 255) << 16) | ((uint32_t)(v.w & 255) << 24);
  }
  __syncthreads();

  const int tid = threadIdx.x;
  const int lane = tid & 63;
  const int wid = tid >> 6;
  const int r0 = blockIdx.y * TILE_M + wid;
  const int cbase = blockIdx.x * TILE_N + lane;
  uint32_t acc[CPL] = {};

  for (int kb = 0; kb < K; kb += KCHUNK) {
    const float4* sa = (const float4*)(A + (size_t)r0 * K + kb);
    uint4 ap = make_uint4(pack4f(sa[0]), pack4f(sa[1]), pack4f(sa[2]), pack4f(sa[3]));
    uint4 wp[CPL];
#pragma unroll
    for (int j = 0; j < CPL; j++) {
      const float4* s = (const float4*)(W + (size_t)(cbase + j * 64) * K + kb);
      wp[j] = make_uint4(pack4f(s[0]), pack4f(s[1]), pack4f(s[2]), pack4f(s[3]));
    }
#pragma unroll
    for (int kk = 0; kk < KCHUNK; kk++) {
      uint32_t as = bsel(ap, kk) << 8;
      uint32_t ws[CPL];
#pragma unroll
      for (int j = 0; j < CPL; j++) ws[j] = bsel(wp[j], kk);
#pragma unroll
      for (int j = 0; j < CPL; j++)
        acc[j] += lut[as | ws[j]];
    }
  }

#pragma unroll
  for (int j = 0; j < CPL; j++) {
    int c = cbase + j * 64;
    out[(size_t)r0 * N + c] = (float)acc[j] + bias[c];
  }
}

extern "C" void kernel_launch(void* const* d_in, const int* in_sizes, int n_in,
                              void* d_out, int out_size, void* d_ws, size_t ws_size,
                              hipStream_t stream) {
  const float* inp  = (const float*)d_in[0];  // [M][K]
  const float* wgt  = (const float*)d_in[1];  // [N][K]
  const float* bias = (const float*)d_in[2];  // [N]
  const int*   lut  = (const int*)d_in[3];    // [256][256]

  const int N = in_sizes[2];
  const int K = in_sizes[1] / N;
  const int M = in_sizes[0] / K;
  float* out = (float*)d_out;

  dim3 grid(N / TILE_N, M / TILE_M);
  size_t need = 65536 + (size_t)M * K + (size_t)N * K;

  if (ws_size >= need) {
    uint8_t* lut8 = (uint8_t*)d_ws;
    uint8_t* a8   = lut8 + 65536;
    uint8_t* wt8  = a8 + (size_t)M * K;
    pack_lut_k<<<16, 256, 0, stream>>>(lut, lut8, 65536 / 16);
    int an16 = (M * K) / 16;
    pack_a_k<<<(an16 + 255) / 256, 256, 0, stream>>>(inp, a8, an16);
    int wn16 = (N * K) / 16;
    pack_w_k<<<(wn16 + 255) / 256, 256, 0, stream>>>(wgt, wt8, N, K);
    lutmm_packed<<<grid, NTHREADS, 0, stream>>>(a8, wt8, lut8, bias, out, M, N, K);
  } else {
    lutmm_f32<<<grid, NTHREADS, 0, stream>>>(inp, wgt, lut, bias, out, M, N, K);
  }
}